// Round 11
// baseline (197.047 us; speedup 1.0000x reference)
//
#include <hip/hip_runtime.h>

typedef unsigned short u16;
typedef short short8 __attribute__((ext_vector_type(8)));
typedef unsigned short ushort8 __attribute__((ext_vector_type(8)));
typedef float floatx16 __attribute__((ext_vector_type(16)));

// ---- sizes (ushort units unless noted) ----
// maskedC layout: [n 8][cg8 32][r 66][c 34][j 8] bf16 -- parity-COMPRESSED
//   padded checkerboard: only (h+w)-odd pixels kept; row r+1 holds input row r,
//   col j+1 holds pixel w = 2j + ((r+1)&1). Borders zero.
#define PLANE8C  17952          // 66*34*8
#define NSTRIDEC 574464         // 32*PLANE8C
// t1 layout (dense): [n 8][cg 16][half 2][r 66][c 66][j 8] bf16 (padded, swizzled)
#define PLANE8   34848          // 66*66*8
#define NSTRIDE  1115136        // 16*2*PLANE8
// t2 layout: [n 8][co 256][pix 4096] bf16 (plane, matches preds_T flat index)
// T  layout: [n 8][pix 4096][ci 128] bf16 (transposed preds_S; overlays t2 region)
// Wsw layout: [cg 16][ct 4][d 1152][j 8] bf16 ; d = tap*128 + sc*64 + cihalf*32 + colow
// Wb  layout: [k 8][cog 8][lane 64][j 8] bf16 ; co=cog*32+(lane&31), ci=k*16+(lane>>5)*8+j
// part layout: [slot 96][bid 512] fp32 ; slot: 0..7 pp, 8..15 tt, 16..79 pt(i*8+j)
// R8 lesson: no contended atomic reductions (33k atomics on 6 cache lines=220us).
// R11: kred+k4 fused via last-block pattern (distinct-address atomics only);
// kconvs BK=2 (2 cg per LDS buffer, halves barrier count).

__device__ __forceinline__ u16 f2b(float f) {
  unsigned u = __builtin_bit_cast(unsigned, f);
  return (u16)((u + 0x7FFFu + ((u >> 16) & 1u)) >> 16);
}
__device__ __forceinline__ float b2f(u16 b) {
  return __builtin_bit_cast(float, ((unsigned)b) << 16);
}

typedef const __attribute__((address_space(1))) unsigned int* gptr_t;
typedef __attribute__((address_space(3))) unsigned int* sptr_t;

// ---------------------------------------------------------------------------
// kprep: fused prep work, block-range dispatch.
//   [0,288):    kwc W_gen1 -> Wsw1
//   [288,576):  kwc W_gen2 -> Wsw2
//   [576,592):  kwa W_align fp32 -> Wb bf16 (MFMA B-fragment layout)
//   [592,1104): kst preds_S [n][ci][pix] fp32 -> T [n][pix][ci] bf16 (LDS transpose)
//   [1104,1360):kzc border zeroing of compressed maskedC (256 planes)
//   [1360,1616):kzd border zeroing of dense t1 (256 planes)
//   1616:       zero kred2 completion counter
// ---------------------------------------------------------------------------
__global__ __launch_bounds__(256) void kprep(
    const float* __restrict__ Wg1, u16* __restrict__ Wsw1,
    const float* __restrict__ Wg2, u16* __restrict__ Wsw2,
    const float* __restrict__ Wa,  u16* __restrict__ Wb,
    const float* __restrict__ pS,  u16* __restrict__ T,
    u16* __restrict__ maskedC, u16* __restrict__ t1,
    unsigned int* __restrict__ cnt)
{
  // stride 136 u16 = 272 B = 17*16 -> aligned ushort8 drain reads.
  __shared__ u16 Ls[64 * 136];   // 17408 B
  int b = blockIdx.x, t = threadIdx.x;

  if (b < 576) {
    // ---- kwc: 3x3 weights fp32 [co][ci][3][3] -> Wsw bf16 ----
    const float* W = (b < 288) ? Wg1 : Wg2;
    u16* D = (b < 288) ? Wsw1 : Wsw2;
    int bb = (b < 288) ? b : b - 288;
    int cid = bb * 256 + t;                        // < 73728
    int d = cid % 1152, ctcg = cid / 1152;
    int ct = ctcg & 3, cg = ctcg >> 2;
    int colow = d & 31, cihalf = (d >> 5) & 1, sc = (d >> 6) & 1, tap = d >> 7;
    int co = ct * 64 + sc * 32 + colow;
    short8 v;
    #pragma unroll
    for (int jj = 0; jj < 8; ++jj) {
      int ci = cg * 16 + cihalf * 8 + jj;
      v[jj] = (short)f2b(W[((size_t)(co * 256 + ci)) * 9 + tap]);
    }
    *(short8*)&D[(size_t)cid * 8] = v;
  } else if (b < 592) {
    // ---- kwa: 1x1 weights fp32 [co 256][ci 128] -> Wb bf16 ----
    int v = (b - 576) * 256 + t;                   // < 4096
    int colow = v & 31, hfb = (v >> 5) & 1, cog = (v >> 6) & 7, k = v >> 9;
    int co = cog * 32 + colow;
    int ci0 = k * 16 + hfb * 8;
    float4 f0 = *(const float4*)(Wa + (size_t)co * 128 + ci0);
    float4 f1 = *(const float4*)(Wa + (size_t)co * 128 + ci0 + 4);
    short8 o;
    o[0] = (short)f2b(f0.x); o[1] = (short)f2b(f0.y);
    o[2] = (short)f2b(f0.z); o[3] = (short)f2b(f0.w);
    o[4] = (short)f2b(f1.x); o[5] = (short)f2b(f1.y);
    o[6] = (short)f2b(f1.z); o[7] = (short)f2b(f1.w);
    *(short8*)&Wb[(size_t)v * 8] = o;
  } else if (b < 1104) {
    // ---- kst: transpose 64pix x 128ci tile, fp32 -> bf16 ----
    int bb = b - 592;                              // < 512
    int n = bb >> 6, pt = bb & 63, pix0 = pt * 64;
    int ci = t >> 1, ph = t & 1;
    const float* src = pS + ((size_t)n * 128 + ci) * 4096 + pix0 + ph * 32;
    #pragma unroll
    for (int i = 0; i < 8; ++i) {
      float4 v4 = *(const float4*)(src + i * 4);
      int pix = ph * 32 + i * 4;
      Ls[(pix + 0) * 136 + ci] = f2b(v4.x);
      Ls[(pix + 1) * 136 + ci] = f2b(v4.y);
      Ls[(pix + 2) * 136 + ci] = f2b(v4.z);
      Ls[(pix + 3) * 136 + ci] = f2b(v4.w);
    }
    __syncthreads();
    int p = t >> 2, q = t & 3;
    const u16* row = Ls + p * 136 + q * 32;
    u16* dst = T + ((size_t)n * 4096 + pix0 + p) * 128 + q * 32;
    #pragma unroll
    for (int k2 = 0; k2 < 4; ++k2)
      *(ushort8*)(dst + k2 * 8) = *(const ushort8*)(row + k2 * 8);
  } else if (b < 1360) {
    // ---- kzc: zero borders of compressed maskedC planes ----
    int p = b - 1104;                              // < 256
    u16* base = maskedC + (size_t)(p >> 5) * NSTRIDEC + (size_t)(p & 31) * PLANE8C;
    short8 z;
    #pragma unroll
    for (int jj = 0; jj < 8; ++jj) z[jj] = 0;
    if (t < 200) {
      int off;
      if (t < 34)       off = t * 8;                        // row 0
      else if (t < 68)  off = (65 * 34 + (t - 34)) * 8;     // row 65
      else if (t < 134) off = ((t - 68) * 34) * 8;          // col 0
      else              off = ((t - 134) * 34 + 33) * 8;    // col 33
      *(short8*)(base + off) = z;
    }
  } else if (b < 1616) {
    // ---- kzd: zero borders of dense t1 planes ----
    int p = b - 1360;                              // < 256
    u16* base = t1 + (size_t)(p >> 5) * NSTRIDE + (size_t)(p & 31) * PLANE8;
    short8 z;
    #pragma unroll
    for (int jj = 0; jj < 8; ++jj) z[jj] = 0;
    #pragma unroll
    for (int pass = 0; pass < 2; ++pass) {
      int seg = t + pass * 256;
      if (seg < 264) {
        int off;
        if (seg < 66)       off = seg * 8;                    // row 0
        else if (seg < 132) off = (65 * 66 + (seg - 66)) * 8; // row 65
        else if (seg < 198) off = ((seg - 132) * 66) * 8;     // col 0
        else                off = ((seg - 198) * 66 + 65) * 8;// col 65
        *(short8*)(base + off) = z;
      }
    }
  } else {
    if (t == 0) *cnt = 0u;   // visible to kred2 via kernel-boundary ordering
  }
}

// ---------------------------------------------------------------------------
// k1m: 1x1 conv as bf16 MFMA GEMM + bias + checkerboard, COMPRESSED store:
// only (h+w)-odd pixels are written (even ones are zero and never stored).
// grid 256 = n(8) x pixtile(32 of 128 pix); block 256 thr = 4 waves.
// ---------------------------------------------------------------------------
__global__ __launch_bounds__(256) void k1m(const u16* __restrict__ T,
    const u16* __restrict__ Wb, const float* __restrict__ ba,
    u16* __restrict__ mk)
{
  __shared__ __align__(16) u16 Wl[32768];   // 64 KB
  int b = blockIdx.x;
  int n = b >> 5, pt = b & 31;
  int t = threadIdx.x, wid = t >> 6, lane = t & 63;
  int ml = lane & 31, hf = lane >> 5;

  #pragma unroll
  for (int kk = 0; kk < 16; ++kk) {
    int chunk = kk * 256 + t;
    __builtin_amdgcn_global_load_lds((gptr_t)(const void*)(Wb + (size_t)chunk * 8),
                                     (sptr_t)(void*)(Wl + chunk * 8), 16, 0, 0);
  }

  const u16* Tn = T + (size_t)n * 524288;
  const u16* ap[4];
  #pragma unroll
  for (int g = 0; g < 4; ++g)
    ap[g] = Tn + (size_t)(pt * 128 + g * 32 + ml) * 128 + hf * 8;

  floatx16 acc[2][4];   // [q co-sub][g pix-group]
  #pragma unroll
  for (int q = 0; q < 2; ++q)
    #pragma unroll
    for (int g = 0; g < 4; ++g)
      #pragma unroll
      for (int i = 0; i < 16; ++i) acc[q][g][i] = 0.f;

  __syncthreads();   // weights resident

  const short8* WlV = (const short8*)Wl;
  int cogb = wid * 2;   // wave's 2 co-groups (co 64)

  short8 a0[4], a1[4];
  #pragma unroll
  for (int g = 0; g < 4; ++g) a0[g] = *(const short8*)(ap[g]);

#define K1M_STEP(K, CUR, NXT, LAST)                                           \
  {                                                                           \
    if (!(LAST)) {                                                            \
      _Pragma("unroll")                                                       \
      for (int g = 0; g < 4; ++g)                                             \
        NXT[g] = *(const short8*)(ap[g] + ((K) + 1) * 16);                    \
    }                                                                         \
    short8 w0 = WlV[((K) * 8 + cogb) * 64 + lane];                            \
    short8 w1 = WlV[((K) * 8 + cogb + 1) * 64 + lane];                        \
    _Pragma("unroll")                                                         \
    for (int g = 0; g < 4; ++g) {                                             \
      acc[0][g] = __builtin_amdgcn_mfma_f32_32x32x16_bf16(CUR[g], w0, acc[0][g], 0, 0, 0); \
      acc[1][g] = __builtin_amdgcn_mfma_f32_32x32x16_bf16(CUR[g], w1, acc[1][g], 0, 0, 0); \
    }                                                                         \
  }
  K1M_STEP(0, a0, a1, 0)
  K1M_STEP(1, a1, a0, 0)
  K1M_STEP(2, a0, a1, 0)
  K1M_STEP(3, a1, a0, 0)
  K1M_STEP(4, a0, a1, 0)
  K1M_STEP(5, a1, a0, 0)
  K1M_STEP(6, a0, a1, 0)
  K1M_STEP(7, a1, a0, 1)
#undef K1M_STEP

  int co0 = cogb * 32 + ml, co1 = co0 + 32;
  float b0 = ba[co0], b1 = ba[co1];
  u16* base0 = mk + (size_t)n * NSTRIDEC + (size_t)(co0 >> 3) * PLANE8C + (co0 & 7);
  u16* base1 = mk + (size_t)n * NSTRIDEC + (size_t)(co1 >> 3) * PLANE8C + (co1 & 7);
  #pragma unroll
  for (int g = 0; g < 4; ++g)
    #pragma unroll
    for (int reg = 0; reg < 16; ++reg) {
      int m = (reg & 3) + 8 * (reg >> 2) + 4 * hf;
      int pix = pt * 128 + g * 32 + m;
      int h = pix >> 6, w = pix & 63;
      if (((h + w) & 1) == 1) {      // uniform across wave for fixed (g,reg)
        int j = (w - ((h + 1) & 1)) >> 1;
        int off = ((h + 1) * 34 + 1 + j) * 8;
        base0[off] = f2b(acc[0][g][reg] + b0);
        base1[off] = f2b(acc[1][g][reg] + b1);
      }
    }
}

// ---------------------------------------------------------------------------
// kconvs: SPARSE 3x3 conv (gen1) on compressed checkerboard input, BK=2.
// grid 256 = n(8) x ct(4) x rowtile(8); block 512 thr = 8 waves; wave wid
// owns output row oh = h0+wid, e = wid&1.
// Per cg: even outputs use taps 1,3,5,7; odd outputs taps 0,2,4,6,8 (exact).
// BK=2: each LDS buffer holds 2 cg (in 12288 + w 18432 u16 = 61440 B);
// dbuf 122880 B, 1 block/CU (unchanged). Barriers 17 -> 9.
// ---------------------------------------------------------------------------
__global__ __launch_bounds__(512) void kconvs(
    const u16* __restrict__ IN, const u16* __restrict__ WS,
    const float* __restrict__ bg, u16* __restrict__ OUT)
{
  __shared__ __align__(16) u16 L[61440];   // 122880 B
  u16* LA = L;            // buffer A: in[2][6144] | w[2][9216]
  u16* LB = L + 30720;    // buffer B

  int b = blockIdx.x;
  int rt = b & 7, ct = (b >> 3) & 3, n = b >> 5;
  int h0 = rt * 8;
  int t = threadIdx.x;
  int wid = t >> 6, lane = t & 63;
  int hf = lane >> 5, ml = lane & 31;
  int e = wid & 1;

  const u16* inb = IN + (size_t)n * NSTRIDEC;
  const u16* wg  = WS + (size_t)ct * 1152 * 8;

  floatx16 acc[2][2];   // [parity p][co-sub q]
  #pragma unroll
  for (int p = 0; p < 2; ++p)
    #pragma unroll
    for (int q = 0; q < 2; ++q)
      #pragma unroll
      for (int i = 0; i < 16; ++i) acc[p][q][i] = 0.f;

  // Stage one cg PAIR (cg = 2*cgp, 2*cgp+1): 60 segs over 8 waves.
  // Per c: weights 18 segs, input 12 segs (2 halves x 6 of 64 chunks).
  auto STAGE2 = [&](int cgp, u16* B) {
    u16* inD = B;            // 12288 u16 (2 x 6144)
    u16* LwD = B + 12288;    // 18432 u16 (2 x 9216)
    #pragma unroll
    for (int k = 0; k < 8; ++k) {
      int seg = wid + 8 * k;          // 0..63
      if (seg < 60) {
        int c = seg >= 30 ? 1 : 0;
        int ss = seg - c * 30;
        int cg = cgp * 2 + c;
        if (ss < 18) {
          const u16* src = wg + (size_t)cg * 36864 + (size_t)(ss * 64 + lane) * 8;
          __builtin_amdgcn_global_load_lds((gptr_t)(const void*)src,
                                           (sptr_t)(void*)(LwD + c * 9216 + ss * 512),
                                           16, 0, 0);
        } else {
          int ii = ss - 18;
          int hh = ii >= 6 ? 1 : 0;
          int s = ii - hh * 6;
          const u16* src = inb + (size_t)cg * (2 * PLANE8C) + (size_t)hh * PLANE8C
                           + (size_t)(h0 * 34 + s * 64 + lane) * 8;
          __builtin_amdgcn_global_load_lds((gptr_t)(const void*)src,
                                           (sptr_t)(void*)(inD + c * 6144 + (hh * 384 + s * 64) * 8),
                                           16, 0, 0);
        }
      }
    }
  };

  // Compute both cg of a buffer.
  auto COMPUTE2 = [&](const u16* B) {
    #pragma unroll
    for (int c = 0; c < 2; ++c) {
      const short8* LinV = (const short8*)B + c * 768;            // chunk units
      const short8* LwV  = (const short8*)B + 1536 + c * 1152;
      int rA = hf * 384 + wid * 34 + 1 + ml;        // above row, col base
      int rS = rA + 34;                             // same row
      int rB = rA + 68;                             // below row
      short8 iA0 = LinV[rA];
      short8 iS0 = LinV[rS];
      short8 iB0 = LinV[rB];
      short8 iSm = LinV[rS + e - 1];
      short8 iSp = LinV[rS + e];
      short8 iAm = LinV[rA - e];
      short8 iAp = LinV[rA + 1 - e];
      short8 iBm = LinV[rB - e];
      short8 iBp = LinV[rB + 1 - e];
      #pragma unroll
      for (int q = 0; q < 2; ++q) {
        short8 w0 = LwV[0 * 128 + q * 64 + lane];
        short8 w1 = LwV[1 * 128 + q * 64 + lane];
        short8 w2 = LwV[2 * 128 + q * 64 + lane];
        short8 w3 = LwV[3 * 128 + q * 64 + lane];
        short8 w4 = LwV[4 * 128 + q * 64 + lane];
        short8 w5 = LwV[5 * 128 + q * 64 + lane];
        short8 w6 = LwV[6 * 128 + q * 64 + lane];
        short8 w7 = LwV[7 * 128 + q * 64 + lane];
        short8 w8 = LwV[8 * 128 + q * 64 + lane];
        // even outputs: taps 1,3,5,7 (relative order preserved vs dense)
        acc[0][q] = __builtin_amdgcn_mfma_f32_32x32x16_bf16(iA0, w1, acc[0][q], 0, 0, 0);
        acc[0][q] = __builtin_amdgcn_mfma_f32_32x32x16_bf16(iSm, w3, acc[0][q], 0, 0, 0);
        acc[0][q] = __builtin_amdgcn_mfma_f32_32x32x16_bf16(iSp, w5, acc[0][q], 0, 0, 0);
        acc[0][q] = __builtin_amdgcn_mfma_f32_32x32x16_bf16(iB0, w7, acc[0][q], 0, 0, 0);
        // odd outputs: taps 0,2,4,6,8
        acc[1][q] = __builtin_amdgcn_mfma_f32_32x32x16_bf16(iAm, w0, acc[1][q], 0, 0, 0);
        acc[1][q] = __builtin_amdgcn_mfma_f32_32x32x16_bf16(iAp, w2, acc[1][q], 0, 0, 0);
        acc[1][q] = __builtin_amdgcn_mfma_f32_32x32x16_bf16(iS0, w4, acc[1][q], 0, 0, 0);
        acc[1][q] = __builtin_amdgcn_mfma_f32_32x32x16_bf16(iBm, w6, acc[1][q], 0, 0, 0);
        acc[1][q] = __builtin_amdgcn_mfma_f32_32x32x16_bf16(iBp, w8, acc[1][q], 0, 0, 0);
      }
    }
  };

  STAGE2(0, LA);
  __syncthreads();
  for (int p = 0; p < 8; p += 2) {
    STAGE2(p + 1, LB);
    COMPUTE2(LA);
    __syncthreads();
    if (p + 2 < 8) STAGE2(p + 2, LA);
    COMPUTE2(LB);
    __syncthreads();
  }

  float bias0 = bg[ct * 64 + ml];        // q=0
  float bias1 = bg[ct * 64 + 32 + ml];   // q=1

  // dense swizzled padded store to t1; out-row oh=h0+wid.
  u16* ob = OUT + (size_t)n * NSTRIDE;
  int co0 = ct * 64 + ml, co1 = co0 + 32;
  int cb0 = ((co0 >> 4) * 2 + ((co0 >> 3) & 1)) * PLANE8 + (co0 & 7);
  int cb1 = ((co1 >> 4) * 2 + ((co1 >> 3) & 1)) * PLANE8 + (co1 & 7);
  int rowoff = (h0 + wid + 1) * 66 + 1;
  #pragma unroll
  for (int reg = 0; reg < 16; ++reg) {
    int m = (reg & 3) + 8 * (reg >> 2) + 4 * hf;
    int we = 2 * m + e, wo = 2 * m + 1 - e;
    float v;
    v = acc[0][0][reg] + bias0; v = fmaxf(v, 0.f); ob[cb0 + (rowoff + we) * 8] = f2b(v);
    v = acc[0][1][reg] + bias1; v = fmaxf(v, 0.f); ob[cb1 + (rowoff + we) * 8] = f2b(v);
    v = acc[1][0][reg] + bias0; v = fmaxf(v, 0.f); ob[cb0 + (rowoff + wo) * 8] = f2b(v);
    v = acc[1][1][reg] + bias1; v = fmaxf(v, 0.f); ob[cb1 + (rowoff + wo) * 8] = f2b(v);
  }
}

// ---------------------------------------------------------------------------
// kconv: DENSE 3x3 conv (gen2), unchanged R5/R9-proven kernel, MODE 1 only.
// grid 256 = n(8) x ct(4) x rowtile(8); block 512 thr = 8 waves.
// ---------------------------------------------------------------------------
template <int MODE>
__global__ __launch_bounds__(512) void kconv(
    const u16* __restrict__ IN, const u16* __restrict__ WS,
    const float* __restrict__ bg, u16* __restrict__ OUT)
{
  __shared__ __align__(16) u16 L[40960];   // 81920 B
  u16* LinA = L;              // 11264 u16 (2 x 704 chunks)
  u16* LwA  = L + 11264;      //  9216 u16 (1152 chunks)
  u16* LinB = L + 20480;      // 11264 u16
  u16* LwB  = L + 31744;      //  9216 u16

  int b = blockIdx.x;
  int rt = b & 7, ct = (b >> 3) & 3, n = b >> 5;
  int h0 = rt * 8;
  int t = threadIdx.x;
  int wid = t >> 6, lane = t & 63;
  int hf = lane >> 5, ml = lane & 31;

  const u16* inb = IN + (size_t)n * NSTRIDE;
  const u16* wg  = WS + (size_t)ct * 1152 * 8;

  floatx16 acc[2][2];   // [colhalf s][co-sub q]; wave owns out-row h0+wid
  #pragma unroll
  for (int s = 0; s < 2; ++s)
    #pragma unroll
    for (int q = 0; q < 2; ++q)
      #pragma unroll
      for (int i = 0; i < 16; ++i) acc[s][q][i] = 0.f;

  auto STAGE = [&](int cg, u16* LinD, u16* LwD) {
    #pragma unroll
    for (int k = 0; k < 3; ++k) {
      int sidx = 8 * k + wid;
      if (sidx < 18) {
        const u16* src = wg + (size_t)cg * 36864 + (size_t)(sidx * 64 + lane) * 8;
        __builtin_amdgcn_global_load_lds((gptr_t)(const void*)src,
                                         (sptr_t)(void*)(LwD + sidx * 512), 16, 0, 0);
      }
    }
    #pragma unroll
    for (int k = 0; k < 3; ++k) {
      int seg = 8 * k + wid;
      if (seg < 22) {
        int half = seg >= 11 ? 1 : 0;
        int s = seg - half * 11;
        const u16* src = inb + (size_t)cg * 69696 + half * PLANE8
                         + (size_t)(h0 * 66 + s * 64 + lane) * 8;
        __builtin_amdgcn_global_load_lds((gptr_t)(const void*)src,
                                         (sptr_t)(void*)(LinD + (half * 704 + s * 64) * 8),
                                         16, 0, 0);
      }
    }
  };

  auto COMPUTE = [&](const u16* LinS, const u16* LwS) {
    const short8* LinV = (const short8*)LinS;
    const short8* LwV  = (const short8*)LwS;
    #pragma unroll
    for (int dr = 0; dr < 3; ++dr) {
      int r0 = hf * 704 + (wid + dr) * 66;
      #pragma unroll
      for (int dc = 0; dc < 3; ++dc) {
        int tap = dr * 3 + dc;
        short8 w0 = LwV[tap * 128 + lane];
        short8 w1 = LwV[tap * 128 + 64 + lane];
        short8 i0 = LinV[r0 + ml + dc];
        short8 i1 = LinV[r0 + 32 + ml + dc];
        acc[0][0] = __builtin_amdgcn_mfma_f32_32x32x16_bf16(i0, w0, acc[0][0], 0, 0, 0);
        acc[0][1] = __builtin_amdgcn_mfma_f32_32x32x16_bf16(i0, w1, acc[0][1], 0, 0, 0);
        acc[1][0] = __builtin_amdgcn_mfma_f32_32x32x16_bf16(i1, w0, acc[1][0], 0, 0, 0);
        acc[1][1] = __builtin_amdgcn_mfma_f32_32x32x16_bf16(i1, w1, acc[1][1], 0, 0, 0);
      }
    }
  };

  STAGE(0, LinA, LwA);
  __syncthreads();
  for (int cg = 0; cg < 16; cg += 2) {
    STAGE(cg + 1, LinB, LwB);
    COMPUTE(LinA, LwA);
    __syncthreads();
    if (cg + 2 < 16) STAGE(cg + 2, LinA, LwA);
    COMPUTE(LinB, LwB);
    __syncthreads();
  }

  float bias0 = bg[ct * 64 + ml];        // q=0
  float bias1 = bg[ct * 64 + 32 + ml];   // q=1

  if (MODE == 0) {
    u16* ob = OUT + (size_t)n * NSTRIDE;
    int co0 = ct * 64 + ml, co1 = co0 + 32;
    int cb0 = ((co0 >> 4) * 2 + ((co0 >> 3) & 1)) * PLANE8 + (co0 & 7);
    int cb1 = ((co1 >> 4) * 2 + ((co1 >> 3) & 1)) * PLANE8 + (co1 & 7);
    int rowoff = (h0 + wid + 1) * 66 + 1;
    #pragma unroll
    for (int reg = 0; reg < 16; ++reg) {
      int m = (reg & 3) + 8 * (reg >> 2) + 4 * hf;
      float v;
      v = acc[0][0][reg] + bias0; v = fmaxf(v, 0.f); ob[cb0 + (rowoff + m) * 8] = f2b(v);
      v = acc[0][1][reg] + bias1; v = fmaxf(v, 0.f); ob[cb1 + (rowoff + m) * 8] = f2b(v);
      v = acc[1][0][reg] + bias0; v = fmaxf(v, 0.f); ob[cb0 + (rowoff + 32 + m) * 8] = f2b(v);
      v = acc[1][1][reg] + bias1; v = fmaxf(v, 0.f); ob[cb1 + (rowoff + 32 + m) * 8] = f2b(v);
    }
  } else {
    // LDS transpose -> plane [n][co][4096]; per-wave plane 64co x 64col,
    // stride 68 u16, disjoint 4352-u16 regions (8 x 4352 = 34816 <= 40960).
    u16* plane = L + wid * 4352;
    #pragma unroll
    for (int reg = 0; reg < 16; ++reg) {
      int m = (reg & 3) + 8 * (reg >> 2) + 4 * hf;
      plane[ml * 68 + m]              = f2b(acc[0][0][reg] + bias0);
      plane[(32 + ml) * 68 + m]       = f2b(acc[0][1][reg] + bias1);
      plane[ml * 68 + 32 + m]         = f2b(acc[1][0][reg] + bias0);
      plane[(32 + ml) * 68 + 32 + m]  = f2b(acc[1][1][reg] + bias1);
    }
    const u16* row = plane + lane * 68;   // co_local = lane
    __align__(16) u16 tmp[64];
    #pragma unroll
    for (int k2 = 0; k2 < 16; ++k2)
      *(ushort4*)(tmp + k2 * 4) = *(const ushort4*)(row + k2 * 4);
    u16* gdst = OUT + (size_t)n * 1048576 + (size_t)(ct * 64 + lane) * 4096
                + (h0 + wid) * 64;
    #pragma unroll
    for (int k2 = 0; k2 < 8; ++k2)
      *(ushort8*)(gdst + k2 * 8) = *(const ushort8*)(tmp + k2 * 8);
  }
}

// ---------------------------------------------------------------------------
// kbmc: fused reduction over d (plane layouts match). No atomics (R8 lesson).
// ---------------------------------------------------------------------------
__global__ __launch_bounds__(256) void kbmc(const u16* __restrict__ t2,
    const float* __restrict__ pT, float* __restrict__ part)
{
  int t = threadIdx.x, lane = t & 63, role = t >> 6;
  int ih = role >> 1, nh = role & 1;
  int bid = blockIdx.x;

  float pt[4][4], pp[4], tt[4];
  #pragma unroll
  for (int i = 0; i < 4; ++i) {
    pp[i] = 0.f; tt[i] = 0.f;
    #pragma unroll
    for (int j = 0; j < 4; ++j) pt[i][j] = 0.f;
  }

  const float* pb = pT + ((size_t)ih * 4) * 1048576;
  const u16*   tb = t2 + ((size_t)nh * 4) * 1048576;

  for (int k = 0; k < 8; ++k) {
    size_t d0 = ((size_t)(bid * 512 + k * 64 + lane)) * 4;
    float4 p[4], tf[4];
    #pragma unroll
    for (int i = 0; i < 4; ++i)
      p[i] = *(const float4*)(pb + (size_t)i * 1048576 + d0);
    #pragma unroll
    for (int j = 0; j < 4; ++j) {
      ushort4 tv = *(const ushort4*)(tb + (size_t)j * 1048576 + d0);
      tf[j] = make_float4(b2f(tv.x), b2f(tv.y), b2f(tv.z), b2f(tv.w));
    }
    if (nh == 0) {
      #pragma unroll
      for (int i = 0; i < 4; ++i)
        pp[i] += p[i].x * p[i].x + p[i].y * p[i].y + p[i].z * p[i].z + p[i].w * p[i].w;
    }
    if (ih == 0) {
      #pragma unroll
      for (int j = 0; j < 4; ++j)
        tt[j] += tf[j].x * tf[j].x + tf[j].y * tf[j].y + tf[j].z * tf[j].z + tf[j].w * tf[j].w;
    }
    #pragma unroll
    for (int i = 0; i < 4; ++i)
      #pragma unroll
      for (int j = 0; j < 4; ++j)
        pt[i][j] += p[i].x * tf[j].x + p[i].y * tf[j].y
                  + p[i].z * tf[j].z + p[i].w * tf[j].w;
  }

  #pragma unroll
  for (int m = 1; m < 64; m <<= 1) {
    #pragma unroll
    for (int i = 0; i < 4; ++i) {
      pp[i] += __shfl_xor(pp[i], m);
      tt[i] += __shfl_xor(tt[i], m);
      #pragma unroll
      for (int j = 0; j < 4; ++j) pt[i][j] += __shfl_xor(pt[i][j], m);
    }
  }
  if (lane == 0) {
    #pragma unroll
    for (int i = 0; i < 4; ++i)
      #pragma unroll
      for (int j = 0; j < 4; ++j)
        part[(size_t)(16 + (ih * 4 + i) * 8 + (nh * 4 + j)) * 512 + bid] = pt[i][j];
    if (nh == 0) {
      #pragma unroll
      for (int i = 0; i < 4; ++i) part[(size_t)(ih * 4 + i) * 512 + bid] = pp[i];
    }
    if (ih == 0) {
      #pragma unroll
      for (int j = 0; j < 4; ++j) part[(size_t)(8 + nh * 4 + j) * 512 + bid] = tt[j];
    }
  }
}

// ---------------------------------------------------------------------------
// kred2: fused kred + k4_final via last-block-done pattern. 80 blocks.
// Block s reduces part[s][*] -> accums[s] (device-scope atomicExch, distinct
// addresses -- NOT R8's contended pattern), then signals a counter; the last
// block to finish acquires and runs the 8x8 logsumexp finisher on wave 0.
// ---------------------------------------------------------------------------
__global__ __launch_bounds__(256) void kred2(const float* __restrict__ part,
    float* __restrict__ accums, unsigned int* __restrict__ cnt,
    float* __restrict__ out)
{
  __shared__ float r4[4];
  __shared__ int last;
  int s = blockIdx.x, t = threadIdx.x, lane = t & 63, wid = t >> 6;
  float v = part[(size_t)s * 512 + t] + part[(size_t)s * 512 + 256 + t];
  #pragma unroll
  for (int m = 1; m < 64; m <<= 1) v += __shfl_xor(v, m);
  if (lane == 0) r4[wid] = v;
  __syncthreads();
  if (t == 0) {
    atomicExch(&accums[s], r4[0] + r4[1] + r4[2] + r4[3]);  // device-visible
    __threadfence();                                         // release
    unsigned int old = atomicAdd(cnt, 1u);
    last = (old == 79u) ? 1 : 0;
  }
  __syncthreads();
  if (last && t < 64) {
    __threadfence();                 // acquire
    int i = t >> 3, j = t & 7;
    double pp = (double)atomicAdd(&accums[i], 0.0f);          // atomic read
    double tt = (double)atomicAdd(&accums[8 + j], 0.0f);
    double pt = (double)atomicAdd(&accums[16 + i * 8 + j], 0.0f);
    double logit = -0.5 * (pp + tt - 2.0 * pt) / 64.0;
    double m = logit;
    #pragma unroll
    for (int ss = 1; ss < 8; ss <<= 1) {
      double o = __shfl_xor(m, ss);
      m = o > m ? o : m;
    }
    double e = exp(logit - m);
    #pragma unroll
    for (int ss = 1; ss < 8; ss <<= 1) e += __shfl_xor(e, ss);
    double lse = m + log(e);
    double term = (j == i) ? (lse - logit) : 0.0;
    #pragma unroll
    for (int ss = 1; ss < 64; ss <<= 1) term += __shfl_xor(term, ss);
    if (t == 0) {
      double ce = term / 8.0;
      out[0] = (float)(ce * (2.0 * 64.0) / 8.0 * 2e-05);
    }
  }
}

// ---------------------------------------------------------------------------
extern "C" void kernel_launch(void* const* d_in, const int* in_sizes, int n_in,
                              void* d_out, int out_size, void* d_ws, size_t ws_size,
                              hipStream_t stream)
{
  const float* preds_S = (const float*)d_in[0];
  const float* preds_T = (const float*)d_in[1];
  const float* W_align = (const float*)d_in[2];
  const float* b_align = (const float*)d_in[3];
  const float* W_gen1  = (const float*)d_in[4];
  const float* b_gen1  = (const float*)d_in[5];
  const float* W_gen2  = (const float*)d_in[6];
  const float* b_gen2  = (const float*)d_in[7];
  float* out = (float*)d_out;

  char* wsb = (char*)d_ws;
  u16* maskedC = (u16*)wsb;                         //  9,191,424 B (compressed)
  u16* t1     = (u16*)(wsb + 9191424);              // 17,842,176 B (dense padded)
  u16* t2p    = (u16*)(wsb + 27033600);             // 16,777,216 B (plane [n][co][pix])
  u16* T      = t2p;                                //  8,388,608 B (overlay; dead after k1m)
  u16* Wsw1   = (u16*)(wsb + 43810816);             //  1,179,648 B
  u16* Wsw2   = (u16*)(wsb + 44990464);             //  1,179,648 B
  float* part   = (float*)(wsb + 46170112);         //    196,608 B [96][512]
  float* accums = (float*)(wsb + 46366720);         //        384 B
  u16* Wb     = (u16*)(wsb + 46367104);             //     65,536 B
  unsigned int* cnt = (unsigned int*)(wsb + 46432640); //       4 B

  kprep<<<1617, 256, 0, stream>>>(W_gen1, Wsw1, W_gen2, Wsw2, W_align, Wb,
                                  preds_S, T, maskedC, t1, cnt);
  k1m<<<256, 256, 0, stream>>>(T, Wb, b_align, maskedC);
  kconvs<<<256, 512, 0, stream>>>(maskedC, Wsw1, b_gen1, t1);     // sparse gen1
  kconv<1><<<256, 512, 0, stream>>>(t1, Wsw2, b_gen2, t2p);       // dense gen2
  kbmc<<<512, 256, 0, stream>>>(t2p, preds_T, part);
  kred2<<<80, 256, 0, stream>>>(part, accums, cnt, out);
}

// Round 12
// 192.372 us; speedup vs baseline: 1.0243x; 1.0243x over previous
//
#include <hip/hip_runtime.h>

typedef unsigned short u16;
typedef short short8 __attribute__((ext_vector_type(8)));
typedef unsigned short ushort8 __attribute__((ext_vector_type(8)));
typedef float floatx16 __attribute__((ext_vector_type(16)));

// ---- sizes (ushort units unless noted) ----
// maskedC layout: [n 8][cg8 32][r 66][c 34][j 8] bf16 -- parity-COMPRESSED
//   padded checkerboard: only (h+w)-odd pixels kept; row r+1 holds input row r,
//   col j+1 holds pixel w = 2j + ((r+1)&1). Borders zero.
#define PLANE8C  17952          // 66*34*8
#define NSTRIDEC 574464         // 32*PLANE8C
// t1 layout (dense): [n 8][cg 16][half 2][r 66][c 66][j 8] bf16 (padded, swizzled)
#define PLANE8   34848          // 66*66*8
#define NSTRIDE  1115136        // 16*2*PLANE8
// t2 layout: [n 8][co 256][pix 4096] bf16 (plane, matches preds_T flat index)
// T  layout: [n 8][pix 4096][ci 128] bf16 (transposed preds_S; overlays t2 region)
// Wsw layout: [cg 16][ct 4][d 1152][j 8] bf16 ; d = tap*128 + sc*64 + cihalf*32 + colow
// Wb  layout: [k 8][cog 8][lane 64][j 8] bf16 ; co=cog*32+(lane&31), ci=k*16+(lane>>5)*8+j
// part layout: [slot 96][bid 512] fp32 ; slot: 0..7 pp, 8..15 tt, 16..79 pt(i*8+j)
// Session ledger (final): R10 config = verified best (193.1us, absmax 0).
//  - R8: no contended atomic reductions (33k atomics / 6 cache lines = 220us).
//  - R4: no single-block reduction fusion (serializes).
//  - R7: coarse counted-vmcnt regresses; 2-phase dbuf ceiling ~900TF stands.
//  - R11: BK=2 + last-block fusion net-negative; reverted.
//  - R10 win: parity-sparse gen1 (half MFMA, exact) -- kept.

__device__ __forceinline__ u16 f2b(float f) {
  unsigned u = __builtin_bit_cast(unsigned, f);
  return (u16)((u + 0x7FFFu + ((u >> 16) & 1u)) >> 16);
}
__device__ __forceinline__ float b2f(u16 b) {
  return __builtin_bit_cast(float, ((unsigned)b) << 16);
}

typedef const __attribute__((address_space(1))) unsigned int* gptr_t;
typedef __attribute__((address_space(3))) unsigned int* sptr_t;

// ---------------------------------------------------------------------------
// kprep: fused prep work, block-range dispatch.
//   [0,288):    kwc W_gen1 -> Wsw1
//   [288,576):  kwc W_gen2 -> Wsw2
//   [576,592):  kwa W_align fp32 -> Wb bf16 (MFMA B-fragment layout)
//   [592,1104): kst preds_S [n][ci][pix] fp32 -> T [n][pix][ci] bf16 (LDS transpose)
//   [1104,1360):kzc border zeroing of compressed maskedC (256 planes)
//   [1360,1616):kzd border zeroing of dense t1 (256 planes)
// ---------------------------------------------------------------------------
__global__ __launch_bounds__(256) void kprep(
    const float* __restrict__ Wg1, u16* __restrict__ Wsw1,
    const float* __restrict__ Wg2, u16* __restrict__ Wsw2,
    const float* __restrict__ Wa,  u16* __restrict__ Wb,
    const float* __restrict__ pS,  u16* __restrict__ T,
    u16* __restrict__ maskedC, u16* __restrict__ t1)
{
  // stride 136 u16 = 272 B = 17*16 -> aligned ushort8 drain reads.
  __shared__ u16 Ls[64 * 136];   // 17408 B
  int b = blockIdx.x, t = threadIdx.x;

  if (b < 576) {
    // ---- kwc: 3x3 weights fp32 [co][ci][3][3] -> Wsw bf16 ----
    const float* W = (b < 288) ? Wg1 : Wg2;
    u16* D = (b < 288) ? Wsw1 : Wsw2;
    int bb = (b < 288) ? b : b - 288;
    int cid = bb * 256 + t;                        // < 73728
    int d = cid % 1152, ctcg = cid / 1152;
    int ct = ctcg & 3, cg = ctcg >> 2;
    int colow = d & 31, cihalf = (d >> 5) & 1, sc = (d >> 6) & 1, tap = d >> 7;
    int co = ct * 64 + sc * 32 + colow;
    short8 v;
    #pragma unroll
    for (int jj = 0; jj < 8; ++jj) {
      int ci = cg * 16 + cihalf * 8 + jj;
      v[jj] = (short)f2b(W[((size_t)(co * 256 + ci)) * 9 + tap]);
    }
    *(short8*)&D[(size_t)cid * 8] = v;
  } else if (b < 592) {
    // ---- kwa: 1x1 weights fp32 [co 256][ci 128] -> Wb bf16 ----
    int v = (b - 576) * 256 + t;                   // < 4096
    int colow = v & 31, hfb = (v >> 5) & 1, cog = (v >> 6) & 7, k = v >> 9;
    int co = cog * 32 + colow;
    int ci0 = k * 16 + hfb * 8;
    float4 f0 = *(const float4*)(Wa + (size_t)co * 128 + ci0);
    float4 f1 = *(const float4*)(Wa + (size_t)co * 128 + ci0 + 4);
    short8 o;
    o[0] = (short)f2b(f0.x); o[1] = (short)f2b(f0.y);
    o[2] = (short)f2b(f0.z); o[3] = (short)f2b(f0.w);
    o[4] = (short)f2b(f1.x); o[5] = (short)f2b(f1.y);
    o[6] = (short)f2b(f1.z); o[7] = (short)f2b(f1.w);
    *(short8*)&Wb[(size_t)v * 8] = o;
  } else if (b < 1104) {
    // ---- kst: transpose 64pix x 128ci tile, fp32 -> bf16 ----
    int bb = b - 592;                              // < 512
    int n = bb >> 6, pt = bb & 63, pix0 = pt * 64;
    int ci = t >> 1, ph = t & 1;
    const float* src = pS + ((size_t)n * 128 + ci) * 4096 + pix0 + ph * 32;
    #pragma unroll
    for (int i = 0; i < 8; ++i) {
      float4 v4 = *(const float4*)(src + i * 4);
      int pix = ph * 32 + i * 4;
      Ls[(pix + 0) * 136 + ci] = f2b(v4.x);
      Ls[(pix + 1) * 136 + ci] = f2b(v4.y);
      Ls[(pix + 2) * 136 + ci] = f2b(v4.z);
      Ls[(pix + 3) * 136 + ci] = f2b(v4.w);
    }
    __syncthreads();
    int p = t >> 2, q = t & 3;
    const u16* row = Ls + p * 136 + q * 32;
    u16* dst = T + ((size_t)n * 4096 + pix0 + p) * 128 + q * 32;
    #pragma unroll
    for (int k2 = 0; k2 < 4; ++k2)
      *(ushort8*)(dst + k2 * 8) = *(const ushort8*)(row + k2 * 8);
  } else if (b < 1360) {
    // ---- kzc: zero borders of compressed maskedC planes ----
    int p = b - 1104;                              // < 256
    u16* base = maskedC + (size_t)(p >> 5) * NSTRIDEC + (size_t)(p & 31) * PLANE8C;
    short8 z;
    #pragma unroll
    for (int jj = 0; jj < 8; ++jj) z[jj] = 0;
    if (t < 200) {
      int off;
      if (t < 34)       off = t * 8;                        // row 0
      else if (t < 68)  off = (65 * 34 + (t - 34)) * 8;     // row 65
      else if (t < 134) off = ((t - 68) * 34) * 8;          // col 0
      else              off = ((t - 134) * 34 + 33) * 8;    // col 33
      *(short8*)(base + off) = z;
    }
  } else {
    // ---- kzd: zero borders of dense t1 planes ----
    int p = b - 1360;                              // < 256
    u16* base = t1 + (size_t)(p >> 5) * NSTRIDE + (size_t)(p & 31) * PLANE8;
    short8 z;
    #pragma unroll
    for (int jj = 0; jj < 8; ++jj) z[jj] = 0;
    #pragma unroll
    for (int pass = 0; pass < 2; ++pass) {
      int seg = t + pass * 256;
      if (seg < 264) {
        int off;
        if (seg < 66)       off = seg * 8;                    // row 0
        else if (seg < 132) off = (65 * 66 + (seg - 66)) * 8; // row 65
        else if (seg < 198) off = ((seg - 132) * 66) * 8;     // col 0
        else                off = ((seg - 198) * 66 + 65) * 8;// col 65
        *(short8*)(base + off) = z;
      }
    }
  }
}

// ---------------------------------------------------------------------------
// k1m: 1x1 conv as bf16 MFMA GEMM + bias + checkerboard, COMPRESSED store:
// only (h+w)-odd pixels are written (even ones are zero and never stored).
// grid 256 = n(8) x pixtile(32 of 128 pix); block 256 thr = 4 waves.
// ---------------------------------------------------------------------------
__global__ __launch_bounds__(256) void k1m(const u16* __restrict__ T,
    const u16* __restrict__ Wb, const float* __restrict__ ba,
    u16* __restrict__ mk)
{
  __shared__ __align__(16) u16 Wl[32768];   // 64 KB
  int b = blockIdx.x;
  int n = b >> 5, pt = b & 31;
  int t = threadIdx.x, wid = t >> 6, lane = t & 63;
  int ml = lane & 31, hf = lane >> 5;

  #pragma unroll
  for (int kk = 0; kk < 16; ++kk) {
    int chunk = kk * 256 + t;
    __builtin_amdgcn_global_load_lds((gptr_t)(const void*)(Wb + (size_t)chunk * 8),
                                     (sptr_t)(void*)(Wl + chunk * 8), 16, 0, 0);
  }

  const u16* Tn = T + (size_t)n * 524288;
  const u16* ap[4];
  #pragma unroll
  for (int g = 0; g < 4; ++g)
    ap[g] = Tn + (size_t)(pt * 128 + g * 32 + ml) * 128 + hf * 8;

  floatx16 acc[2][4];   // [q co-sub][g pix-group]
  #pragma unroll
  for (int q = 0; q < 2; ++q)
    #pragma unroll
    for (int g = 0; g < 4; ++g)
      #pragma unroll
      for (int i = 0; i < 16; ++i) acc[q][g][i] = 0.f;

  __syncthreads();   // weights resident

  const short8* WlV = (const short8*)Wl;
  int cogb = wid * 2;   // wave's 2 co-groups (co 64)

  short8 a0[4], a1[4];
  #pragma unroll
  for (int g = 0; g < 4; ++g) a0[g] = *(const short8*)(ap[g]);

#define K1M_STEP(K, CUR, NXT, LAST)                                           \
  {                                                                           \
    if (!(LAST)) {                                                            \
      _Pragma("unroll")                                                       \
      for (int g = 0; g < 4; ++g)                                             \
        NXT[g] = *(const short8*)(ap[g] + ((K) + 1) * 16);                    \
    }                                                                         \
    short8 w0 = WlV[((K) * 8 + cogb) * 64 + lane];                            \
    short8 w1 = WlV[((K) * 8 + cogb + 1) * 64 + lane];                        \
    _Pragma("unroll")                                                         \
    for (int g = 0; g < 4; ++g) {                                             \
      acc[0][g] = __builtin_amdgcn_mfma_f32_32x32x16_bf16(CUR[g], w0, acc[0][g], 0, 0, 0); \
      acc[1][g] = __builtin_amdgcn_mfma_f32_32x32x16_bf16(CUR[g], w1, acc[1][g], 0, 0, 0); \
    }                                                                         \
  }
  K1M_STEP(0, a0, a1, 0)
  K1M_STEP(1, a1, a0, 0)
  K1M_STEP(2, a0, a1, 0)
  K1M_STEP(3, a1, a0, 0)
  K1M_STEP(4, a0, a1, 0)
  K1M_STEP(5, a1, a0, 0)
  K1M_STEP(6, a0, a1, 0)
  K1M_STEP(7, a1, a0, 1)
#undef K1M_STEP

  int co0 = cogb * 32 + ml, co1 = co0 + 32;
  float b0 = ba[co0], b1 = ba[co1];
  u16* base0 = mk + (size_t)n * NSTRIDEC + (size_t)(co0 >> 3) * PLANE8C + (co0 & 7);
  u16* base1 = mk + (size_t)n * NSTRIDEC + (size_t)(co1 >> 3) * PLANE8C + (co1 & 7);
  #pragma unroll
  for (int g = 0; g < 4; ++g)
    #pragma unroll
    for (int reg = 0; reg < 16; ++reg) {
      int m = (reg & 3) + 8 * (reg >> 2) + 4 * hf;
      int pix = pt * 128 + g * 32 + m;
      int h = pix >> 6, w = pix & 63;
      if (((h + w) & 1) == 1) {      // uniform across wave for fixed (g,reg)
        int j = (w - ((h + 1) & 1)) >> 1;
        int off = ((h + 1) * 34 + 1 + j) * 8;
        base0[off] = f2b(acc[0][g][reg] + b0);
        base1[off] = f2b(acc[1][g][reg] + b1);
      }
    }
}

// ---------------------------------------------------------------------------
// kconvs: SPARSE 3x3 conv (gen1) on compressed checkerboard input.
// grid 256 = n(8) x ct(4) x rowtile(8); block 512 thr = 8 waves; wave wid
// owns output row oh = h0+wid, e = oh&1 = wid&1 (h0 multiple of 8).
// Even-parity outputs (ow=2m+e): taps (0,1)@A0, (1,0)@S(e-1), (1,2)@S(e),
// (2,1)@B0. Odd outputs (ow=2m+1-e): (0,0)@A(-e), (0,2)@A(1-e), (1,1)@S0,
// (2,0)@B(-e), (2,2)@B(1-e).  A/S/B = compressed padded rows oh-1/oh/oh+1
// (local rows wid/wid+1/wid+2), col base 1+ml.
// 18 MFMA + 9 i-reads + 18 w-reads per wave per cg (half of dense).
// LDS: in 2x384 chunks + w 1152 chunks per buffer = 30720 B; dbuf 61440 B.
// Store: dense swizzled padded t1 (+bias, relu), both parities.
// Exact vs dense: zero-input taps contributed exactly +0 in fp32.
// ---------------------------------------------------------------------------
__global__ __launch_bounds__(512) void kconvs(
    const u16* __restrict__ IN, const u16* __restrict__ WS,
    const float* __restrict__ bg, u16* __restrict__ OUT)
{
  __shared__ __align__(16) u16 L[30720];   // 61440 B
  u16* LinA = L;              //  6144 u16 (2 x 384 chunks)
  u16* LwA  = L + 6144;       //  9216 u16
  u16* LinB = L + 15360;      //  6144 u16
  u16* LwB  = L + 21504;      //  9216 u16

  int b = blockIdx.x;
  int rt = b & 7, ct = (b >> 3) & 3, n = b >> 5;
  int h0 = rt * 8;
  int t = threadIdx.x;
  int wid = t >> 6, lane = t & 63;
  int hf = lane >> 5, ml = lane & 31;
  int e = wid & 1;

  const u16* inb = IN + (size_t)n * NSTRIDEC;
  const u16* wg  = WS + (size_t)ct * 1152 * 8;

  floatx16 acc[2][2];   // [parity p][co-sub q]
  #pragma unroll
  for (int p = 0; p < 2; ++p)
    #pragma unroll
    for (int q = 0; q < 2; ++q)
      #pragma unroll
      for (int i = 0; i < 16; ++i) acc[p][q][i] = 0.f;

  // 30 segs/cg over 8 waves: 0..17 weights, 18..29 input (2 halves x 6 of 64
  // chunks; rows h0..h0+9 = 340 chunks + 44 staged-garbage never read).
  auto STAGE = [&](int cg, u16* LinD, u16* LwD) {
    #pragma unroll
    for (int k = 0; k < 4; ++k) {
      int seg = wid + 8 * k;
      if (seg < 18) {
        const u16* src = wg + (size_t)cg * 36864 + (size_t)(seg * 64 + lane) * 8;
        __builtin_amdgcn_global_load_lds((gptr_t)(const void*)src,
                                         (sptr_t)(void*)(LwD + seg * 512), 16, 0, 0);
      } else if (seg < 30) {
        int ii = seg - 18;
        int hh = ii >= 6 ? 1 : 0;
        int s = ii - hh * 6;
        const u16* src = inb + (size_t)cg * (2 * PLANE8C) + (size_t)hh * PLANE8C
                         + (size_t)(h0 * 34 + s * 64 + lane) * 8;
        __builtin_amdgcn_global_load_lds((gptr_t)(const void*)src,
                                         (sptr_t)(void*)(LinD + (hh * 384 + s * 64) * 8),
                                         16, 0, 0);
      }
    }
  };

  auto COMPUTE = [&](const u16* LinS, const u16* LwS) {
    const short8* LinV = (const short8*)LinS;
    const short8* LwV  = (const short8*)LwS;
    int rA = hf * 384 + wid * 34 + 1 + ml;        // above row, col base
    int rS = rA + 34;                             // same row
    int rB = rA + 68;                             // below row
    short8 iA0 = LinV[rA];
    short8 iS0 = LinV[rS];
    short8 iB0 = LinV[rB];
    short8 iSm = LinV[rS + e - 1];
    short8 iSp = LinV[rS + e];
    short8 iAm = LinV[rA - e];
    short8 iAp = LinV[rA + 1 - e];
    short8 iBm = LinV[rB - e];
    short8 iBp = LinV[rB + 1 - e];
    #pragma unroll
    for (int q = 0; q < 2; ++q) {
      short8 w0 = LwV[0 * 128 + q * 64 + lane];
      short8 w1 = LwV[1 * 128 + q * 64 + lane];
      short8 w2 = LwV[2 * 128 + q * 64 + lane];
      short8 w3 = LwV[3 * 128 + q * 64 + lane];
      short8 w4 = LwV[4 * 128 + q * 64 + lane];
      short8 w5 = LwV[5 * 128 + q * 64 + lane];
      short8 w6 = LwV[6 * 128 + q * 64 + lane];
      short8 w7 = LwV[7 * 128 + q * 64 + lane];
      short8 w8 = LwV[8 * 128 + q * 64 + lane];
      // even outputs: taps 1,3,5,7 (relative order preserved vs dense)
      acc[0][q] = __builtin_amdgcn_mfma_f32_32x32x16_bf16(iA0, w1, acc[0][q], 0, 0, 0);
      acc[0][q] = __builtin_amdgcn_mfma_f32_32x32x16_bf16(iSm, w3, acc[0][q], 0, 0, 0);
      acc[0][q] = __builtin_amdgcn_mfma_f32_32x32x16_bf16(iSp, w5, acc[0][q], 0, 0, 0);
      acc[0][q] = __builtin_amdgcn_mfma_f32_32x32x16_bf16(iB0, w7, acc[0][q], 0, 0, 0);
      // odd outputs: taps 0,2,4,6,8
      acc[1][q] = __builtin_amdgcn_mfma_f32_32x32x16_bf16(iAm, w0, acc[1][q], 0, 0, 0);
      acc[1][q] = __builtin_amdgcn_mfma_f32_32x32x16_bf16(iAp, w2, acc[1][q], 0, 0, 0);
      acc[1][q] = __builtin_amdgcn_mfma_f32_32x32x16_bf16(iS0, w4, acc[1][q], 0, 0, 0);
      acc[1][q] = __builtin_amdgcn_mfma_f32_32x32x16_bf16(iBm, w6, acc[1][q], 0, 0, 0);
      acc[1][q] = __builtin_amdgcn_mfma_f32_32x32x16_bf16(iBp, w8, acc[1][q], 0, 0, 0);
    }
  };

  STAGE(0, LinA, LwA);
  __syncthreads();
  for (int cg = 0; cg < 16; cg += 2) {
    STAGE(cg + 1, LinB, LwB);
    COMPUTE(LinA, LwA);
    __syncthreads();
    if (cg + 2 < 16) STAGE(cg + 2, LinA, LwA);
    COMPUTE(LinB, LwB);
    __syncthreads();
  }

  float bias0 = bg[ct * 64 + ml];        // q=0
  float bias1 = bg[ct * 64 + 32 + ml];   // q=1

  // dense swizzled padded store to t1; out-row oh=h0+wid.
  u16* ob = OUT + (size_t)n * NSTRIDE;
  int co0 = ct * 64 + ml, co1 = co0 + 32;
  int cb0 = ((co0 >> 4) * 2 + ((co0 >> 3) & 1)) * PLANE8 + (co0 & 7);
  int cb1 = ((co1 >> 4) * 2 + ((co1 >> 3) & 1)) * PLANE8 + (co1 & 7);
  int rowoff = (h0 + wid + 1) * 66 + 1;
  #pragma unroll
  for (int reg = 0; reg < 16; ++reg) {
    int m = (reg & 3) + 8 * (reg >> 2) + 4 * hf;
    int we = 2 * m + e, wo = 2 * m + 1 - e;
    float v;
    v = acc[0][0][reg] + bias0; v = fmaxf(v, 0.f); ob[cb0 + (rowoff + we) * 8] = f2b(v);
    v = acc[0][1][reg] + bias1; v = fmaxf(v, 0.f); ob[cb1 + (rowoff + we) * 8] = f2b(v);
    v = acc[1][0][reg] + bias0; v = fmaxf(v, 0.f); ob[cb0 + (rowoff + wo) * 8] = f2b(v);
    v = acc[1][1][reg] + bias1; v = fmaxf(v, 0.f); ob[cb1 + (rowoff + wo) * 8] = f2b(v);
  }
}

// ---------------------------------------------------------------------------
// kconv: DENSE 3x3 conv (gen2), R5/R9-proven kernel, MODE 1 only.
// grid 256 = n(8) x ct(4) x rowtile(8); block 512 thr = 8 waves.
// ---------------------------------------------------------------------------
template <int MODE>
__global__ __launch_bounds__(512) void kconv(
    const u16* __restrict__ IN, const u16* __restrict__ WS,
    const float* __restrict__ bg, u16* __restrict__ OUT)
{
  __shared__ __align__(16) u16 L[40960];   // 81920 B
  u16* LinA = L;              // 11264 u16 (2 x 704 chunks)
  u16* LwA  = L + 11264;      //  9216 u16 (1152 chunks)
  u16* LinB = L + 20480;      // 11264 u16
  u16* LwB  = L + 31744;      //  9216 u16

  int b = blockIdx.x;
  int rt = b & 7, ct = (b >> 3) & 3, n = b >> 5;
  int h0 = rt * 8;
  int t = threadIdx.x;
  int wid = t >> 6, lane = t & 63;
  int hf = lane >> 5, ml = lane & 31;

  const u16* inb = IN + (size_t)n * NSTRIDE;
  const u16* wg  = WS + (size_t)ct * 1152 * 8;

  floatx16 acc[2][2];   // [colhalf s][co-sub q]; wave owns out-row h0+wid
  #pragma unroll
  for (int s = 0; s < 2; ++s)
    #pragma unroll
    for (int q = 0; q < 2; ++q)
      #pragma unroll
      for (int i = 0; i < 16; ++i) acc[s][q][i] = 0.f;

  auto STAGE = [&](int cg, u16* LinD, u16* LwD) {
    #pragma unroll
    for (int k = 0; k < 3; ++k) {
      int sidx = 8 * k + wid;
      if (sidx < 18) {
        const u16* src = wg + (size_t)cg * 36864 + (size_t)(sidx * 64 + lane) * 8;
        __builtin_amdgcn_global_load_lds((gptr_t)(const void*)src,
                                         (sptr_t)(void*)(LwD + sidx * 512), 16, 0, 0);
      }
    }
    #pragma unroll
    for (int k = 0; k < 3; ++k) {
      int seg = 8 * k + wid;
      if (seg < 22) {
        int half = seg >= 11 ? 1 : 0;
        int s = seg - half * 11;
        const u16* src = inb + (size_t)cg * 69696 + half * PLANE8
                         + (size_t)(h0 * 66 + s * 64 + lane) * 8;
        __builtin_amdgcn_global_load_lds((gptr_t)(const void*)src,
                                         (sptr_t)(void*)(LinD + (half * 704 + s * 64) * 8),
                                         16, 0, 0);
      }
    }
  };

  auto COMPUTE = [&](const u16* LinS, const u16* LwS) {
    const short8* LinV = (const short8*)LinS;
    const short8* LwV  = (const short8*)LwS;
    #pragma unroll
    for (int dr = 0; dr < 3; ++dr) {
      int r0 = hf * 704 + (wid + dr) * 66;
      #pragma unroll
      for (int dc = 0; dc < 3; ++dc) {
        int tap = dr * 3 + dc;
        short8 w0 = LwV[tap * 128 + lane];
        short8 w1 = LwV[tap * 128 + 64 + lane];
        short8 i0 = LinV[r0 + ml + dc];
        short8 i1 = LinV[r0 + 32 + ml + dc];
        acc[0][0] = __builtin_amdgcn_mfma_f32_32x32x16_bf16(i0, w0, acc[0][0], 0, 0, 0);
        acc[0][1] = __builtin_amdgcn_mfma_f32_32x32x16_bf16(i0, w1, acc[0][1], 0, 0, 0);
        acc[1][0] = __builtin_amdgcn_mfma_f32_32x32x16_bf16(i1, w0, acc[1][0], 0, 0, 0);
        acc[1][1] = __builtin_amdgcn_mfma_f32_32x32x16_bf16(i1, w1, acc[1][1], 0, 0, 0);
      }
    }
  };

  STAGE(0, LinA, LwA);
  __syncthreads();
  for (int cg = 0; cg < 16; cg += 2) {
    STAGE(cg + 1, LinB, LwB);
    COMPUTE(LinA, LwA);
    __syncthreads();
    if (cg + 2 < 16) STAGE(cg + 2, LinA, LwA);
    COMPUTE(LinB, LwB);
    __syncthreads();
  }

  float bias0 = bg[ct * 64 + ml];        // q=0
  float bias1 = bg[ct * 64 + 32 + ml];   // q=1

  if (MODE == 0) {
    u16* ob = OUT + (size_t)n * NSTRIDE;
    int co0 = ct * 64 + ml, co1 = co0 + 32;
    int cb0 = ((co0 >> 4) * 2 + ((co0 >> 3) & 1)) * PLANE8 + (co0 & 7);
    int cb1 = ((co1 >> 4) * 2 + ((co1 >> 3) & 1)) * PLANE8 + (co1 & 7);
    int rowoff = (h0 + wid + 1) * 66 + 1;
    #pragma unroll
    for (int reg = 0; reg < 16; ++reg) {
      int m = (reg & 3) + 8 * (reg >> 2) + 4 * hf;
      float v;
      v = acc[0][0][reg] + bias0; v = fmaxf(v, 0.f); ob[cb0 + (rowoff + m) * 8] = f2b(v);
      v = acc[0][1][reg] + bias1; v = fmaxf(v, 0.f); ob[cb1 + (rowoff + m) * 8] = f2b(v);
      v = acc[1][0][reg] + bias0; v = fmaxf(v, 0.f); ob[cb0 + (rowoff + 32 + m) * 8] = f2b(v);
      v = acc[1][1][reg] + bias1; v = fmaxf(v, 0.f); ob[cb1 + (rowoff + 32 + m) * 8] = f2b(v);
    }
  } else {
    // LDS transpose -> plane [n][co][4096]; per-wave plane 64co x 64col,
    // stride 68 u16, disjoint 4352-u16 regions (8 x 4352 = 34816 <= 40960).
    u16* plane = L + wid * 4352;
    #pragma unroll
    for (int reg = 0; reg < 16; ++reg) {
      int m = (reg & 3) + 8 * (reg >> 2) + 4 * hf;
      plane[ml * 68 + m]              = f2b(acc[0][0][reg] + bias0);
      plane[(32 + ml) * 68 + m]       = f2b(acc[0][1][reg] + bias1);
      plane[ml * 68 + 32 + m]         = f2b(acc[1][0][reg] + bias0);
      plane[(32 + ml) * 68 + 32 + m]  = f2b(acc[1][1][reg] + bias1);
    }
    const u16* row = plane + lane * 68;   // co_local = lane
    __align__(16) u16 tmp[64];
    #pragma unroll
    for (int k2 = 0; k2 < 16; ++k2)
      *(ushort4*)(tmp + k2 * 4) = *(const ushort4*)(row + k2 * 4);
    u16* gdst = OUT + (size_t)n * 1048576 + (size_t)(ct * 64 + lane) * 4096
                + (h0 + wid) * 64;
    #pragma unroll
    for (int k2 = 0; k2 < 8; ++k2)
      *(ushort8*)(gdst + k2 * 8) = *(const ushort8*)(tmp + k2 * 8);
  }
}

// ---------------------------------------------------------------------------
// kbmc: fused reduction over d (plane layouts match). No atomics (R8 lesson).
// ---------------------------------------------------------------------------
__global__ __launch_bounds__(256) void kbmc(const u16* __restrict__ t2,
    const float* __restrict__ pT, float* __restrict__ part)
{
  int t = threadIdx.x, lane = t & 63, role = t >> 6;
  int ih = role >> 1, nh = role & 1;
  int bid = blockIdx.x;

  float pt[4][4], pp[4], tt[4];
  #pragma unroll
  for (int i = 0; i < 4; ++i) {
    pp[i] = 0.f; tt[i] = 0.f;
    #pragma unroll
    for (int j = 0; j < 4; ++j) pt[i][j] = 0.f;
  }

  const float* pb = pT + ((size_t)ih * 4) * 1048576;
  const u16*   tb = t2 + ((size_t)nh * 4) * 1048576;

  for (int k = 0; k < 8; ++k) {
    size_t d0 = ((size_t)(bid * 512 + k * 64 + lane)) * 4;
    float4 p[4], tf[4];
    #pragma unroll
    for (int i = 0; i < 4; ++i)
      p[i] = *(const float4*)(pb + (size_t)i * 1048576 + d0);
    #pragma unroll
    for (int j = 0; j < 4; ++j) {
      ushort4 tv = *(const ushort4*)(tb + (size_t)j * 1048576 + d0);
      tf[j] = make_float4(b2f(tv.x), b2f(tv.y), b2f(tv.z), b2f(tv.w));
    }
    if (nh == 0) {
      #pragma unroll
      for (int i = 0; i < 4; ++i)
        pp[i] += p[i].x * p[i].x + p[i].y * p[i].y + p[i].z * p[i].z + p[i].w * p[i].w;
    }
    if (ih == 0) {
      #pragma unroll
      for (int j = 0; j < 4; ++j)
        tt[j] += tf[j].x * tf[j].x + tf[j].y * tf[j].y + tf[j].z * tf[j].z + tf[j].w * tf[j].w;
    }
    #pragma unroll
    for (int i = 0; i < 4; ++i)
      #pragma unroll
      for (int j = 0; j < 4; ++j)
        pt[i][j] += p[i].x * tf[j].x + p[i].y * tf[j].y
                  + p[i].z * tf[j].z + p[i].w * tf[j].w;
  }

  #pragma unroll
  for (int m = 1; m < 64; m <<= 1) {
    #pragma unroll
    for (int i = 0; i < 4; ++i) {
      pp[i] += __shfl_xor(pp[i], m);
      tt[i] += __shfl_xor(tt[i], m);
      #pragma unroll
      for (int j = 0; j < 4; ++j) pt[i][j] += __shfl_xor(pt[i][j], m);
    }
  }
  if (lane == 0) {
    #pragma unroll
    for (int i = 0; i < 4; ++i)
      #pragma unroll
      for (int j = 0; j < 4; ++j)
        part[(size_t)(16 + (ih * 4 + i) * 8 + (nh * 4 + j)) * 512 + bid] = pt[i][j];
    if (nh == 0) {
      #pragma unroll
      for (int i = 0; i < 4; ++i) part[(size_t)(ih * 4 + i) * 512 + bid] = pp[i];
    }
    if (ih == 0) {
      #pragma unroll
      for (int j = 0; j < 4; ++j) part[(size_t)(8 + nh * 4 + j) * 512 + bid] = tt[j];
    }
  }
}

// ---------------------------------------------------------------------------
// kred: 80 blocks x 256 threads; block s reduces part[s][0..512) -> accums[s].
// ---------------------------------------------------------------------------
__global__ __launch_bounds__(256) void kred(const float* __restrict__ part,
                                            float* __restrict__ accums)
{
  __shared__ float r4[4];
  int s = blockIdx.x, t = threadIdx.x, lane = t & 63, wid = t >> 6;
  float v = part[(size_t)s * 512 + t] + part[(size_t)s * 512 + 256 + t];
  #pragma unroll
  for (int m = 1; m < 64; m <<= 1) v += __shfl_xor(v, m);
  if (lane == 0) r4[wid] = v;
  __syncthreads();
  if (t == 0) accums[s] = r4[0] + r4[1] + r4[2] + r4[3];
}

// ---------------------------------------------------------------------------
// k4: 8x8 logsumexp finisher, one lane per (i,j) logit; shuffle reductions.
// ---------------------------------------------------------------------------
__global__ void k4_final(const float* __restrict__ accums, float* __restrict__ out)
{
  int t = threadIdx.x;           // 64 threads, lane = i*8 + j
  int i = t >> 3, j = t & 7;
  double pp = accums[i];
  double tt = accums[8 + j];
  double pt = accums[16 + i * 8 + j];
  double logit = -0.5 * (pp + tt - 2.0 * pt) / 64.0;
  double m = logit;
  #pragma unroll
  for (int s = 1; s < 8; s <<= 1) {
    double o = __shfl_xor(m, s);
    m = o > m ? o : m;
  }
  double e = exp(logit - m);
  #pragma unroll
  for (int s = 1; s < 8; s <<= 1) e += __shfl_xor(e, s);
  double lse = m + log(e);
  double term = (j == i) ? (lse - logit) : 0.0;
  #pragma unroll
  for (int s = 1; s < 64; s <<= 1) term += __shfl_xor(term, s);
  if (t == 0) {
    double ce = term / 8.0;
    out[0] = (float)(ce * (2.0 * 64.0) / 8.0 * 2e-05);
  }
}

// ---------------------------------------------------------------------------
extern "C" void kernel_launch(void* const* d_in, const int* in_sizes, int n_in,
                              void* d_out, int out_size, void* d_ws, size_t ws_size,
                              hipStream_t stream)
{
  const float* preds_S = (const float*)d_in[0];
  const float* preds_T = (const float*)d_in[1];
  const float* W_align = (const float*)d_in[2];
  const float* b_align = (const float*)d_in[3];
  const float* W_gen1  = (const float*)d_in[4];
  const float* b_gen1  = (const float*)d_in[5];
  const float* W_gen2  = (const float*)d_in[6];
  const float* b_gen2  = (const float*)d_in[7];
  float* out = (float*)d_out;

  char* wsb = (char*)d_ws;
  u16* maskedC = (u16*)wsb;                         //  9,191,424 B (compressed)
  u16* t1     = (u16*)(wsb + 9191424);              // 17,842,176 B (dense padded)
  u16* t2p    = (u16*)(wsb + 27033600);             // 16,777,216 B (plane [n][co][pix])
  u16* T      = t2p;                                //  8,388,608 B (overlay; dead after k1m)
  u16* Wsw1   = (u16*)(wsb + 43810816);             //  1,179,648 B
  u16* Wsw2   = (u16*)(wsb + 44990464);             //  1,179,648 B
  float* part   = (float*)(wsb + 46170112);         //    196,608 B [96][512]
  float* accums = (float*)(wsb + 46366720);         //        384 B
  u16* Wb     = (u16*)(wsb + 46367104);             //     65,536 B

  kprep<<<1616, 256, 0, stream>>>(W_gen1, Wsw1, W_gen2, Wsw2, W_align, Wb,
                                  preds_S, T, maskedC, t1);
  k1m<<<256, 256, 0, stream>>>(T, Wb, b_align, maskedC);
  kconvs<<<256, 512, 0, stream>>>(maskedC, Wsw1, b_gen1, t1);     // sparse gen1
  kconv<1><<<256, 512, 0, stream>>>(t1, Wsw2, b_gen2, t2p);       // dense gen2
  kbmc<<<512, 256, 0, stream>>>(t2p, preds_T, part);
  kred<<<80, 256, 0, stream>>>(part, accums);
  k4_final<<<1, 64, 0, stream>>>(accums, out);
}